// Round 1
// baseline (596.043 us; speedup 1.0000x reference)
//
#include <hip/hip_runtime.h>
#include <math.h>

#define BB 32
#define TT 2048
#define DD 1024
#define TCHUNK 64

// fast tanh via hardware exp: tanh(x) = 1 - 2/(e^{2x}+1)
// exact at +-inf saturation; |err| ~1e-7 mid-range. Threshold is 2.3e-2.
__device__ __forceinline__ float fast_tanh(float x) {
    float e = __expf(2.0f * x);
    return 1.0f - __fdividef(2.0f, e + 1.0f);
}

// ---------------- kernel 1: energies[b,t] = v . tanh(keys + query + wf) ----
// one block (256 thr) per (t, b); thread i covers d = 4i..4i+3 (float4).
// writes energies into the weights region of d_out (softmax overwrites it
// in place). t >= len[b] is skipped entirely (weights there are 0 anyway).
__global__ __launch_bounds__(256) void energies_kernel(
    const float* __restrict__ keys, const float* __restrict__ query,
    const float* __restrict__ wf, const float* __restrict__ v,
    const int* __restrict__ lenp, float* __restrict__ eout)
{
    const int t = blockIdx.x;
    const int b = blockIdx.y;
    if (t >= lenp[b]) return;           // masked: softmax writes 0 there

    const int d = threadIdx.x * 4;
    const size_t row = ((size_t)b * TT + t) * DD;

    const float4 k4 = *(const float4*)(keys + row + d);
    const float4 w4 = *(const float4*)(wf   + row + d);
    const float4 q4 = *(const float4*)(query + (size_t)b * DD + d);
    const float4 v4 = *(const float4*)(v + d);

    float s = fast_tanh(k4.x + q4.x + w4.x) * v4.x
            + fast_tanh(k4.y + q4.y + w4.y) * v4.y
            + fast_tanh(k4.z + q4.z + w4.z) * v4.z
            + fast_tanh(k4.w + q4.w + w4.w) * v4.w;

    // wave64 reduce, then 4 wave partials through LDS
    #pragma unroll
    for (int off = 32; off > 0; off >>= 1) s += __shfl_down(s, off, 64);
    __shared__ float red[4];
    if ((threadIdx.x & 63) == 0) red[threadIdx.x >> 6] = s;
    __syncthreads();
    if (threadIdx.x == 0)
        eout[(size_t)b * TT + t] = red[0] + red[1] + red[2] + red[3];
}

// ---------------- kernel 2: masked softmax over T, in place ---------------
// one block (256 thr) per b; 8 elements per thread.
__global__ __launch_bounds__(256) void softmax_kernel(
    const int* __restrict__ lenp, float* __restrict__ wrow_all)
{
    const int b = blockIdx.x;
    const int L = lenp[b];
    float* wrow = wrow_all + (size_t)b * TT;

    float e[8];
    float m = -INFINITY;
    #pragma unroll
    for (int i = 0; i < 8; i++) {
        const int t = threadIdx.x + i * 256;
        e[i] = (t < L) ? wrow[t] : -INFINITY;
        m = fmaxf(m, e[i]);
    }
    #pragma unroll
    for (int off = 1; off < 64; off <<= 1) m = fmaxf(m, __shfl_xor(m, off, 64));
    __shared__ float redm[4];
    const int wv = threadIdx.x >> 6;
    if ((threadIdx.x & 63) == 0) redm[wv] = m;
    __syncthreads();
    m = fmaxf(fmaxf(redm[0], redm[1]), fmaxf(redm[2], redm[3]));

    float s = 0.0f;
    #pragma unroll
    for (int i = 0; i < 8; i++) {
        e[i] = (e[i] == -INFINITY) ? 0.0f : __expf(e[i] - m);
        s += e[i];
    }
    #pragma unroll
    for (int off = 1; off < 64; off <<= 1) s += __shfl_xor(s, off, 64);
    __shared__ float reds[4];
    if ((threadIdx.x & 63) == 0) reds[wv] = s;
    __syncthreads();
    s = reds[0] + reds[1] + reds[2] + reds[3];
    const float inv = 1.0f / s;

    #pragma unroll
    for (int i = 0; i < 8; i++)
        wrow[threadIdx.x + i * 256] = e[i] * inv;   // exact 0 for masked t
}

// ---------------- kernel 3: context[b,:] = sum_t w[b,t] * value[b,t,:] ----
// grid (TT/TCHUNK, BB); block covers full D with float4/thread; chunks past
// len[b] exit before loading. Partial sums atomicAdd'd into zeroed context.
__global__ __launch_bounds__(256) void context_kernel(
    const float* __restrict__ value, const float* __restrict__ weights,
    const int* __restrict__ lenp, float* __restrict__ context)
{
    const int b = blockIdx.y;
    const int L = lenp[b];
    const int t0 = blockIdx.x * TCHUNK;
    if (t0 >= L) return;
    const int tend = min(t0 + TCHUNK, L);
    const int d = threadIdx.x * 4;

    float4 acc = make_float4(0.f, 0.f, 0.f, 0.f);
    for (int t = t0; t < tend; t++) {
        const float w = weights[(size_t)b * TT + t];
        const float4 v4 = *(const float4*)(value + ((size_t)b * TT + t) * DD + d);
        acc.x += w * v4.x; acc.y += w * v4.y;
        acc.z += w * v4.z; acc.w += w * v4.w;
    }
    float* dst = context + (size_t)b * DD + d;
    atomicAdd(dst + 0, acc.x);
    atomicAdd(dst + 1, acc.y);
    atomicAdd(dst + 2, acc.z);
    atomicAdd(dst + 3, acc.w);
}

extern "C" void kernel_launch(void* const* d_in, const int* in_sizes, int n_in,
                              void* d_out, int out_size, void* d_ws, size_t ws_size,
                              hipStream_t stream) {
    const float* keys  = (const float*)d_in[0];
    const float* value = (const float*)d_in[1];
    const float* query = (const float*)d_in[2];
    const float* wf    = (const float*)d_in[3];
    const float* v     = (const float*)d_in[4];
    const int*   lenp  = (const int*)d_in[5];

    float* out      = (float*)d_out;
    float* context  = out;               // [B, D]
    float* weights  = out + BB * DD;     // [B, T] (weights[:,:,None] flattened)

    // context accumulated via atomics -> must start at 0 (d_out is poisoned)
    hipMemsetAsync(context, 0, (size_t)BB * DD * sizeof(float), stream);

    energies_kernel<<<dim3(TT, BB), 256, 0, stream>>>(keys, query, wf, v, lenp, weights);
    softmax_kernel<<<BB, 256, 0, stream>>>(lenp, weights);
    context_kernel<<<dim3(TT / TCHUNK, BB), 256, 0, stream>>>(value, weights, lenp, context);
}